// Round 1
// baseline (992.321 us; speedup 1.0000x reference)
//
#include <hip/hip_runtime.h>
#include <cstdint>
#include <cstddef>

// Fused prefix-LM self-attention, B=8192, S=64, D=32, H=4, DH=8, all f32.
// 1 wave per batch item; lane = sequence row. Weights via wave-uniform
// scalar loads (SGPRs). k,v staged in LDS with XOR chunk swizzle
// (writes bank-spread; reads are uniform-address broadcasts).
#define NB 8192
#define NS 64
#define ND 32

__global__ __launch_bounds__(256) void fused_prefix_attn(
    const float* __restrict__ x,
    const int*   __restrict__ aatt,
    const float* __restrict__ Wq, const float* __restrict__ bq,
    const float* __restrict__ Wk, const float* __restrict__ bk,
    const float* __restrict__ Wv, const float* __restrict__ bv,
    const float* __restrict__ Wp, const float* __restrict__ bp,
    float* __restrict__ out)
{
    __shared__ float kl[4][NS][ND];
    __shared__ float vl[4][NS][ND];

    const int wid  = threadIdx.x >> 6;
    const int lane = threadIdx.x & 63;
    const int b    = (blockIdx.x << 2) | wid;

    const size_t rowoff = ((size_t)b * NS + lane) * ND;

    // ---- load x row (32 f32) ----
    float xr[ND];
#pragma unroll
    for (int c = 0; c < ND / 4; ++c) {
        float4 t = reinterpret_cast<const float4*>(x + rowoff)[c];
        xr[4*c+0] = t.x; xr[4*c+1] = t.y; xr[4*c+2] = t.z; xr[4*c+3] = t.w;
    }

    // ---- q/k/v projections: y[o] = sum_d x[d]*W[o*32+d] + b[o] ----
    // W reads are wave-uniform -> s_load (SGPR operands in v_fma).
    float qr[ND];
#pragma unroll
    for (int c = 0; c < ND / 4; ++c) {
        float aq[4], ak[4], av[4];
#pragma unroll
        for (int i = 0; i < 4; ++i) {
            aq[i] = bq[4*c+i]; ak[i] = bk[4*c+i]; av[i] = bv[4*c+i];
        }
#pragma unroll
        for (int d = 0; d < ND; ++d) {
            const float xv = xr[d];
#pragma unroll
            for (int i = 0; i < 4; ++i) {
                aq[i] = fmaf(xv, Wq[(4*c+i)*ND + d], aq[i]);
                ak[i] = fmaf(xv, Wk[(4*c+i)*ND + d], ak[i]);
                av[i] = fmaf(xv, Wv[(4*c+i)*ND + d], av[i]);
            }
        }
#pragma unroll
        for (int i = 0; i < 4; ++i) qr[4*c+i] = aq[i];
        // XOR-swizzled float4 store: chunk c of row `lane` goes to slot c^(lane&7).
        const int cs = c ^ (lane & 7);
        float4 kt; kt.x = ak[0]; kt.y = ak[1]; kt.z = ak[2]; kt.w = ak[3];
        float4 vt; vt.x = av[0]; vt.y = av[1]; vt.z = av[2]; vt.w = av[3];
        *reinterpret_cast<float4*>(&kl[wid][lane][4*cs]) = kt;
        *reinterpret_cast<float4*>(&vl[wid][lane][4*cs]) = vt;
    }

    __syncthreads();

    const int aab = aatt[b];   // prefix length for this batch

    float oacc[ND];
    const float kscale = 0.35355339059327373f;   // 1/sqrt(8)
    const float l2e    = 1.4426950408889634f;    // log2(e)
    const float escale = kscale * l2e;

#pragma unroll
    for (int h = 0; h < 4; ++h) {
        // scores for all 64 keys (raw dot products)
        float sc[NS];
#pragma unroll
        for (int j = 0; j < NS; ++j) {
            const float* kr = &kl[wid][j][0];
            const float4 ka = *reinterpret_cast<const float4*>(kr + 4*((2*h  ) ^ (j & 7)));
            const float4 kb = *reinterpret_cast<const float4*>(kr + 4*((2*h+1) ^ (j & 7)));
            float s;
            s = qr[8*h+0] * ka.x;
            s = fmaf(qr[8*h+1], ka.y, s);
            s = fmaf(qr[8*h+2], ka.z, s);
            s = fmaf(qr[8*h+3], ka.w, s);
            s = fmaf(qr[8*h+4], kb.x, s);
            s = fmaf(qr[8*h+5], kb.y, s);
            s = fmaf(qr[8*h+6], kb.z, s);
            s = fmaf(qr[8*h+7], kb.w, s);
            sc[j] = s;
        }
        // exp (no max-subtraction: |score/sqrt(8)| <~ 2, f32-safe) + mask + sum
        float s0 = 0.f, s1 = 0.f, s2 = 0.f, s3 = 0.f;
#pragma unroll
        for (int j = 0; j < NS; ++j) {
            float e = exp2f(sc[j] * escale);
            e = (j <= lane || j < aab) ? e : 0.0f;
            sc[j] = e;
            if ((j & 3) == 0)      s0 += e;
            else if ((j & 3) == 1) s1 += e;
            else if ((j & 3) == 2) s2 += e;
            else                   s3 += e;
        }
        const float inv = 1.0f / ((s0 + s1) + (s2 + s3));
        // PV
        float oh[8] = {0.f,0.f,0.f,0.f,0.f,0.f,0.f,0.f};
#pragma unroll
        for (int j = 0; j < NS; ++j) {
            const float* vr = &vl[wid][j][0];
            const float4 va = *reinterpret_cast<const float4*>(vr + 4*((2*h  ) ^ (j & 7)));
            const float4 vb = *reinterpret_cast<const float4*>(vr + 4*((2*h+1) ^ (j & 7)));
            const float p = sc[j];
            oh[0] = fmaf(p, va.x, oh[0]); oh[1] = fmaf(p, va.y, oh[1]);
            oh[2] = fmaf(p, va.z, oh[2]); oh[3] = fmaf(p, va.w, oh[3]);
            oh[4] = fmaf(p, vb.x, oh[4]); oh[5] = fmaf(p, vb.y, oh[5]);
            oh[6] = fmaf(p, vb.z, oh[6]); oh[7] = fmaf(p, vb.w, oh[7]);
        }
#pragma unroll
        for (int d = 0; d < 8; ++d) oacc[8*h+d] = oh[d] * inv;
    }

    // ---- final projection + store ----
#pragma unroll
    for (int c = 0; c < ND / 4; ++c) {
        float ao[4];
#pragma unroll
        for (int i = 0; i < 4; ++i) ao[i] = bp[4*c+i];
#pragma unroll
        for (int d = 0; d < ND; ++d) {
#pragma unroll
            for (int i = 0; i < 4; ++i)
                ao[i] = fmaf(oacc[d], Wp[(4*c+i)*ND + d], ao[i]);
        }
        float4 t; t.x = ao[0]; t.y = ao[1]; t.z = ao[2]; t.w = ao[3];
        reinterpret_cast<float4*>(out + rowoff)[c] = t;
    }
}

extern "C" void kernel_launch(void* const* d_in, const int* in_sizes, int n_in,
                              void* d_out, int out_size, void* d_ws, size_t ws_size,
                              hipStream_t stream) {
    const float* x  = (const float*)d_in[0];
    const int*   aa = (const int*)d_in[1];
    const float* Wq = (const float*)d_in[2];
    const float* bq = (const float*)d_in[3];
    const float* Wk = (const float*)d_in[4];
    const float* bk = (const float*)d_in[5];
    const float* Wv = (const float*)d_in[6];
    const float* bv = (const float*)d_in[7];
    const float* Wp = (const float*)d_in[8];
    const float* bp = (const float*)d_in[9];
    float* out = (float*)d_out;

    dim3 grid(NB / 4), block(256);
    hipLaunchKernelGGL(fused_prefix_attn, grid, block, 0, stream,
                       x, aa, Wq, bq, Wk, bk, Wv, bv, Wp, bp, out);
}

// Round 2
// 212.881 us; speedup vs baseline: 4.6614x; 4.6614x over previous
//
#include <hip/hip_runtime.h>
#include <cstdint>
#include <cstddef>

// Fused prefix-LM self-attention, B=8192, S=64, D=32, H=4, DH=8, all f32.
// 1 wave (64-thread block) per batch item; lane = sequence row.
// Weights via wave-uniform scalar loads (SGPRs). k,v staged in LDS with
// XOR chunk swizzle (writes bank-spread; reads are uniform broadcasts).
// Softmax is single-pass streaming (no max-subtraction needed: |score|<~2;
// no score array -> no spills).
#define NB 8192
#define NS 64
#define ND 32

__global__ __launch_bounds__(64, 3) void fused_prefix_attn(
    const float* __restrict__ x,
    const int*   __restrict__ aatt,
    const float* __restrict__ Wq, const float* __restrict__ bq,
    const float* __restrict__ Wk, const float* __restrict__ bk,
    const float* __restrict__ Wv, const float* __restrict__ bv,
    const float* __restrict__ Wp, const float* __restrict__ bp,
    float* __restrict__ out)
{
    __shared__ float kl[NS][ND];
    __shared__ float vl[NS][ND];

    const int lane = threadIdx.x;          // 0..63, = query row
    const int b    = blockIdx.x;           // batch item

    const size_t rowoff = ((size_t)b * NS + lane) * ND;

    // ---- load x row (32 f32) ----
    float xr[ND];
#pragma unroll
    for (int c = 0; c < ND / 4; ++c) {
        float4 t = reinterpret_cast<const float4*>(x + rowoff)[c];
        xr[4*c+0] = t.x; xr[4*c+1] = t.y; xr[4*c+2] = t.z; xr[4*c+3] = t.w;
    }

    // ---- q/k/v projections: y[o] = sum_d x[d]*W[o*32+d] + b[o] ----
    float qr[ND];
#pragma unroll
    for (int c = 0; c < ND / 4; ++c) {
        float aq[4], ak[4], av[4];
#pragma unroll
        for (int i = 0; i < 4; ++i) {
            aq[i] = bq[4*c+i]; ak[i] = bk[4*c+i]; av[i] = bv[4*c+i];
        }
#pragma unroll
        for (int d = 0; d < ND; ++d) {
            const float xv = xr[d];
#pragma unroll
            for (int i = 0; i < 4; ++i) {
                aq[i] = fmaf(xv, Wq[(4*c+i)*ND + d], aq[i]);
                ak[i] = fmaf(xv, Wk[(4*c+i)*ND + d], ak[i]);
                av[i] = fmaf(xv, Wv[(4*c+i)*ND + d], av[i]);
            }
        }
#pragma unroll
        for (int i = 0; i < 4; ++i) qr[4*c+i] = aq[i];
        // XOR-swizzled float4 store: chunk c of row `lane` -> slot c^(lane&7).
        const int cs = c ^ (lane & 7);
        float4 kt; kt.x = ak[0]; kt.y = ak[1]; kt.z = ak[2]; kt.w = ak[3];
        float4 vt; vt.x = av[0]; vt.y = av[1]; vt.z = av[2]; vt.w = av[3];
        *reinterpret_cast<float4*>(&kl[lane][4*cs]) = kt;
        *reinterpret_cast<float4*>(&vl[lane][4*cs]) = vt;
    }

    // fold 1/sqrt(8)*log2(e) into q so the j-loop does exp2f(s) directly
    const float escale = 0.35355339059327373f * 1.4426950408889634f;
#pragma unroll
    for (int d = 0; d < ND; ++d) qr[d] *= escale;

    __syncthreads();

    const int aab = aatt[b];   // prefix length for this batch

    // ---- single-pass streaming attention over keys, all 4 heads fused ----
    float sum[4] = {0.f, 0.f, 0.f, 0.f};
    float oh[4][8] = {};

#pragma unroll 8                 // keeps (j&7) a compile-time constant
    for (int j = 0; j < NS; ++j) {
        const bool allowed_pref = (j < aab);
        float e[4];
#pragma unroll
        for (int h = 0; h < 4; ++h) {
            const float4 ka = *reinterpret_cast<const float4*>(&kl[j][4*((2*h  ) ^ (j & 7))]);
            const float4 kb = *reinterpret_cast<const float4*>(&kl[j][4*((2*h+1) ^ (j & 7))]);
            float s;
            s = qr[8*h+0] * ka.x;
            s = fmaf(qr[8*h+1], ka.y, s);
            s = fmaf(qr[8*h+2], ka.z, s);
            s = fmaf(qr[8*h+3], ka.w, s);
            s = fmaf(qr[8*h+4], kb.x, s);
            s = fmaf(qr[8*h+5], kb.y, s);
            s = fmaf(qr[8*h+6], kb.z, s);
            s = fmaf(qr[8*h+7], kb.w, s);
            float ee = exp2f(s);
            ee = (j <= lane || allowed_pref) ? ee : 0.0f;
            e[h] = ee;
            sum[h] += ee;
        }
#pragma unroll
        for (int h = 0; h < 4; ++h) {
            const float4 va = *reinterpret_cast<const float4*>(&vl[j][4*((2*h  ) ^ (j & 7))]);
            const float4 vb = *reinterpret_cast<const float4*>(&vl[j][4*((2*h+1) ^ (j & 7))]);
            const float p = e[h];
            oh[h][0] = fmaf(p, va.x, oh[h][0]);
            oh[h][1] = fmaf(p, va.y, oh[h][1]);
            oh[h][2] = fmaf(p, va.z, oh[h][2]);
            oh[h][3] = fmaf(p, va.w, oh[h][3]);
            oh[h][4] = fmaf(p, vb.x, oh[h][4]);
            oh[h][5] = fmaf(p, vb.y, oh[h][5]);
            oh[h][6] = fmaf(p, vb.z, oh[h][6]);
            oh[h][7] = fmaf(p, vb.w, oh[h][7]);
        }
    }

    float oacc[ND];
#pragma unroll
    for (int h = 0; h < 4; ++h) {
        const float inv = 1.0f / sum[h];
#pragma unroll
        for (int d = 0; d < 8; ++d) oacc[8*h+d] = oh[h][d] * inv;
    }

    // ---- final projection + store ----
#pragma unroll
    for (int c = 0; c < ND / 4; ++c) {
        float ao[4];
#pragma unroll
        for (int i = 0; i < 4; ++i) ao[i] = bp[4*c+i];
#pragma unroll
        for (int d = 0; d < ND; ++d) {
#pragma unroll
            for (int i = 0; i < 4; ++i)
                ao[i] = fmaf(oacc[d], Wp[(4*c+i)*ND + d], ao[i]);
        }
        float4 t; t.x = ao[0]; t.y = ao[1]; t.z = ao[2]; t.w = ao[3];
        reinterpret_cast<float4*>(out + rowoff)[c] = t;
    }
}

extern "C" void kernel_launch(void* const* d_in, const int* in_sizes, int n_in,
                              void* d_out, int out_size, void* d_ws, size_t ws_size,
                              hipStream_t stream) {
    const float* x  = (const float*)d_in[0];
    const int*   aa = (const int*)d_in[1];
    const float* Wq = (const float*)d_in[2];
    const float* bq = (const float*)d_in[3];
    const float* Wk = (const float*)d_in[4];
    const float* bk = (const float*)d_in[5];
    const float* Wv = (const float*)d_in[6];
    const float* bv = (const float*)d_in[7];
    const float* Wp = (const float*)d_in[8];
    const float* bp = (const float*)d_in[9];
    float* out = (float*)d_out;

    dim3 grid(NB), block(64);
    hipLaunchKernelGGL(fused_prefix_attn, grid, block, 0, stream,
                       x, aa, Wq, bq, Wk, bk, Wv, bv, Wp, bp, out);
}